// Round 7
// baseline (612.473 us; speedup 1.0000x reference)
//
#include <hip/hip_runtime.h>

// Problem constants (GRID=192, ISO=0)
#define GN 192           // grid points per axis
#define CN 193           // cells per axis (GN+1)
#define NROWS (CN * CN)  // 37249 (i,j) k-rows

// Output layout (float32 elements), in reference return order:
//   verts : CN^3 * 3 ; vmask : CN^3 ; quads : 3 * CN*GN*GN * 4 ; qmask : 3 * CN*GN*GN
#define NV        ((size_t)CN * CN * CN)                  // 7,189,057
#define OFF_VMASK ((size_t)(NV * 3))                      // 21,567,171
#define OFF_QUADS ((size_t)(OFF_VMASK + NV))              // 28,756,228 (/4 -> f4-aligned)
#define QSEG      ((size_t)CN * GN * GN)                  // 7,114,752 rows per segment
#define OFF_QMASK ((size_t)(OFF_QUADS + 3 * QSEG * 4))

typedef float f4 __attribute__((ext_vector_type(4)));

__device__ __forceinline__ void nts(float* p, float v) { __builtin_nontemporal_store(v, p); }
__device__ __forceinline__ void nts4(f4* p, f4 v) { __builtin_nontemporal_store(v, p); }

#define NBLK 4096        // persistent blocks, grid-stride over rows

// One block per (i,j) row of 193 cells. The 4 grid rows feeding this cell-row
// ((i-1|i) x (j-1|j)) are staged to LDS via ONE coalesced f4 load per thread
// (192 lanes x 16B = 768B per row), double-buffered: next row's load issues
// before current row's compute, so HBM latency hides under compute+stores.
// Every output of a row is a contiguous run in its segment:
//   verts 579 fl @ row*579, vmask 193 fl, A/B: 192 quads+masks, C: 193.
__global__ __launch_bounds__(256) void dmc_rows(const float* __restrict__ g,
                                                float* __restrict__ out) {
    __shared__ float rows[2][4][194];   // [buf][subrow][pad(1.0) | 192 data | pad(1.0)]
    const int tid = threadIdx.x;

    // constant pads, both buffers, once
    if (tid < 16) rows[tid >> 3][(tid >> 1) & 3][(tid & 1) * 193] = 1.0f;

    const int  rsel   = tid / 48;            // 0..3 = (di,dj) = (rsel>>1, rsel&1)
    const int  f4i    = tid - rsel * 48;     // 0..47 -> 16B chunk within the row
    const bool stager = tid < 192;

    unsigned row = blockIdx.x;

    // prologue: stage first row into buf 0
    if (row < NROWS && stager) {
        const int i = row / CN, j = row - (row / CN) * CN;
        const int gx = i - 1 + (rsel >> 1);
        const int gy = j - 1 + (rsel & 1);
        f4 v = (f4){1.f, 1.f, 1.f, 1.f};
        if ((unsigned)gx < GN && (unsigned)gy < GN)
            v = ((const f4*)(g + ((size_t)gx * GN + gy) * GN))[f4i];
        float* d = &rows[0][rsel][1 + 4 * f4i];
        d[0] = v.x; d[1] = v.y; d[2] = v.z; d[3] = v.w;
    }

    int buf = 0;
    for (; row < NROWS; row += NBLK) {
        __syncthreads();                      // rows[buf] staged & prior readers done

        // issue NEXT row's global loads early; consumed after compute
        const unsigned nrow = row + NBLK;
        const bool havenext = (nrow < NROWS) && stager;
        f4 nxt = (f4){1.f, 1.f, 1.f, 1.f};
        if (havenext) {
            const int ni = nrow / CN, nj = nrow - (nrow / CN) * CN;
            const int gx = ni - 1 + (rsel >> 1);
            const int gy = nj - 1 + (rsel & 1);
            if ((unsigned)gx < GN && (unsigned)gy < GN)
                nxt = ((const f4*)(g + ((size_t)gx * GN + gy) * GN))[f4i];
        }

        // ---- compute & store current row ----
        const int i = row / CN;
        const int j = row - i * CN;
        const int k = tid;
        if (k < CN) {
            const float* r00 = rows[buf][0];
            const float* r01 = rows[buf][1];
            const float* r10 = rows[buf][2];
            const float* r11 = rows[buf][3];
            // corner (dx,dy,dz) = grid[i-1+dx][j-1+dy][k-1+dz] = r{dx}{dy}[k+dz]
            const float v000 = r00[k], v001 = r00[k + 1];
            const float v010 = r01[k], v011 = r01[k + 1];
            const float v100 = r10[k], v101 = r10[k + 1];
            const float v110 = r11[k], v111 = r11[k + 1];

            float sx = 0.f, sy = 0.f, sz = 0.f, cf = 0.f;
            auto acc = [&](float vA, float vB, int axis, float o1, float o2) {
                const bool cr = (vA < 0.f) != (vB < 0.f);
                const float m = cr ? 1.0f : 0.0f;
                const float d = cr ? (vB - vA) : 1.0f;   // safe operand
                float r = __builtin_amdgcn_rcpf(d);
                r = r * (2.0f - d * r);                   // 1 Newton step
                const float t = cr ? (-vA * r) : 0.0f;
                if (axis == 0)      { sx += t;      sy += m * o1; sz += m * o2; }
                else if (axis == 1) { sx += m * o1; sy += t;      sz += m * o2; }
                else                { sx += m * o1; sy += m * o2; sz += t;      }
                cf += m;
            };
            acc(v000, v100, 0, 0.f, 0.f);
            acc(v010, v110, 0, 1.f, 0.f);
            acc(v001, v101, 0, 0.f, 1.f);
            acc(v011, v111, 0, 1.f, 1.f);
            acc(v000, v010, 1, 0.f, 0.f);
            acc(v100, v110, 1, 1.f, 0.f);
            acc(v001, v011, 1, 0.f, 1.f);
            acc(v101, v111, 1, 1.f, 1.f);
            acc(v000, v001, 2, 0.f, 0.f);
            acc(v100, v101, 2, 1.f, 0.f);
            acc(v010, v011, 2, 0.f, 1.f);
            acc(v110, v111, 2, 1.f, 1.f);

            const float cfm = fmaxf(cf, 1.0f);
            float rc = __builtin_amdgcn_rcpf(cfm);
            rc = rc * (2.0f - cfm * rc);
            const float inv191 = 1.0f / 191.0f;

            const int lin = (int)row * CN + k;   // cell id, exact in f32 (<2^23)
            const float flin = (float)lin;

            nts(out + (size_t)lin * 3 + 0, ((float)i + sx * rc - 1.0f) * inv191);
            nts(out + (size_t)lin * 3 + 1, ((float)j + sy * rc - 1.0f) * inv191);
            nts(out + (size_t)lin * 3 + 2, ((float)k + sz * rc - 1.0f) * inv191);
            nts(out + OFF_VMASK + lin, (cf > 0.f) ? 1.0f : 0.0f);

            f4* const quads = (f4*)(out + OFF_QUADS);
            float* const qmask = out + OFF_QMASK;

            // segment A (x-edges): valid j<192 && k<192
            if (j < GN && k < GN) {
                const size_t rA = ((size_t)i * GN + j) * GN + k;
                nts4(quads + rA, (f4){flin, flin + 193.f, flin + 194.f, flin + 1.f});
                nts(qmask + rA, ((v011 < 0.f) != (v111 < 0.f)) ? 1.0f : 0.0f);
            }
            // segment B (y-edges): valid i>=1 && k<192
            if (i >= 1 && k < GN) {
                const size_t rB = QSEG + ((size_t)(i - 1) * CN + j) * GN + k;
                nts4(quads + rB, (f4){flin - 37249.f, flin, flin + 1.f, flin - 37248.f});
                nts(qmask + rB, ((v001 < 0.f) != (v011 < 0.f)) ? 1.0f : 0.0f);
            }
            // segment C (z-edges): valid i>=1 && j>=1
            if (i >= 1 && j >= 1) {
                const size_t rC = 2 * QSEG + ((size_t)(i - 1) * GN + (j - 1)) * CN + k;
                nts4(quads + rC, (f4){flin - 37442.f, flin - 193.f, flin, flin - 37249.f});
                nts(qmask + rC, ((v000 < 0.f) != (v001 < 0.f)) ? 1.0f : 0.0f);
            }
        }

        // write prefetched next row into the other buffer (vmcnt wait lands here,
        // after compute hid the latency); next loop-top barrier publishes it
        if (havenext) {
            float* d = &rows[buf ^ 1][rsel][1 + 4 * f4i];
            d[0] = nxt.x; d[1] = nxt.y; d[2] = nxt.z; d[3] = nxt.w;
        }
        buf ^= 1;
    }
}

extern "C" void kernel_launch(void* const* d_in, const int* in_sizes, int n_in,
                              void* d_out, int out_size, void* d_ws, size_t ws_size,
                              hipStream_t stream) {
    const float* g = (const float*)d_in[0];
    float* out = (float*)d_out;
    dmc_rows<<<dim3(NBLK), dim3(256), 0, stream>>>(g, out);
}